// Round 6
// baseline (318.482 us; speedup 1.0000x reference)
//
#include <hip/hip_runtime.h>
#include <math.h>
#include <stdint.h>

#define IN_DIM 256
#define OUT_D 64
#define ROUTIT 4
#define LCAP 48      // register-cached edges per node (6 groups of 8)
#define NG 6         // LCAP/8 fully-unrolled z-register groups
#define BSH 7        // bucket shift: 128 nodes per bucket
#define NBMAX 512    // supports n up to 65536 (packing needs n <= 65536 too)
#define LOG2E 1.4426950408889634f

// ---- cross-lane helpers (mov_dpp + add folds to v_add_f32_dpp in backend) ----
__device__ __forceinline__ float dpp_add_xor1(float x) {
    return x + __int_as_float(__builtin_amdgcn_mov_dpp(__float_as_int(x), 0xB1, 0xF, 0xF, true));
}
__device__ __forceinline__ float dpp_add_xor2(float x) {
    return x + __int_as_float(__builtin_amdgcn_mov_dpp(__float_as_int(x), 0x4E, 0xF, 0xF, true));
}
__device__ __forceinline__ float dpp_add_xor8(float x) {
    return x + __int_as_float(__builtin_amdgcn_mov_dpp(__float_as_int(x), 0x128, 0xF, 0xF, true));
}
__device__ __forceinline__ float swz_add_xor4(float x) {
    return x + __int_as_float(__builtin_amdgcn_ds_swizzle(__float_as_int(x), 0x101F));
}
__device__ __forceinline__ float swz_add_xor16(float x) {
    return x + __int_as_float(__builtin_amdgcn_ds_swizzle(__float_as_int(x), 0x401F));
}

__device__ __forceinline__ void load8v(float z[8], const float* p) {
    float4 a = *(const float4*)p;
    float4 b = *(const float4*)(p + 4);
    z[0]=a.x; z[1]=a.y; z[2]=a.z; z[3]=a.w;
    z[4]=b.x; z[5]=b.y; z[6]=b.z; z[7]=b.w;
}

// ---------------- h = l2norm(l2norm(leaky_relu(x @ W + b))) ----------------
// v5: 4 rows per lane. The wave-uniform ds_read_b128 broadcast (4 useful floats
// per op) is the bottleneck of v4 (~3.2M LDS ops); feeding 4 rows per broadcast
// quarters it. 196 blocks (1/CU), 8 waves x 8-col slice (one capsule per wave).
__global__ __launch_bounds__(512, 2) void gemm_norm_kernel(
    const float* __restrict__ x, const float* __restrict__ w,
    const float* __restrict__ bias, float* __restrict__ h, int n)
{
    __shared__ float wlds[IN_DIM * OUT_D];   // 64 KB
    {
        const float4* wsrc = (const float4*)w;
        float4* wdst = (float4*)wlds;
        #pragma unroll
        for (int i = 0; i < (IN_DIM * OUT_D / 4); i += 512)
            wdst[i + threadIdx.x] = wsrc[i + threadIdx.x];
    }
    __syncthreads();

    int lane = threadIdx.x & 63;
    int wv   = threadIdx.x >> 6;          // 0..7
    int c0   = wv * 8;                    // this wave's capsule
    int base = blockIdx.x * 256;

    const float* xr[4];
    int rows[4];
    #pragma unroll
    for (int r = 0; r < 4; ++r) {
        rows[r] = base + r * 64 + lane;
        int rc = rows[r] < n ? rows[r] : n - 1;
        xr[r] = x + (size_t)rc * IN_DIM;
    }

    float acc[4][8];
    #pragma unroll
    for (int r = 0; r < 4; ++r)
        #pragma unroll
        for (int c = 0; c < 8; ++c) acc[r][c] = bias[c0 + c];

    float4 xa[4], xb[4];
    #pragma unroll
    for (int r = 0; r < 4; ++r) {
        xa[r] = *(const float4*)(xr[r]);
        xb[r] = *(const float4*)(xr[r] + 4);
    }

    for (int k0 = 0; k0 < IN_DIM; k0 += 8) {
        int kn = (k0 + 8 < IN_DIM) ? k0 + 8 : 0;       // wrap: harmless re-read
        float4 na[4], nb[4];
        #pragma unroll
        for (int r = 0; r < 4; ++r) {
            na[r] = *(const float4*)(xr[r] + kn);
            nb[r] = *(const float4*)(xr[r] + kn + 4);
        }
        const float* wk = wlds + k0 * OUT_D + c0;
        #pragma unroll
        for (int kk = 0; kk < 8; ++kk) {
            float4 w0 = *(const float4*)(wk + kk * OUT_D);      // broadcast b128
            float4 w1 = *(const float4*)(wk + kk * OUT_D + 4);
            #pragma unroll
            for (int r = 0; r < 4; ++r) {
                float xs = (kk < 4)
                    ? ((kk == 0) ? xa[r].x : (kk == 1) ? xa[r].y : (kk == 2) ? xa[r].z : xa[r].w)
                    : ((kk == 4) ? xb[r].x : (kk == 5) ? xb[r].y : (kk == 6) ? xb[r].z : xb[r].w);
                acc[r][0] = fmaf(xs, w0.x, acc[r][0]);
                acc[r][1] = fmaf(xs, w0.y, acc[r][1]);
                acc[r][2] = fmaf(xs, w0.z, acc[r][2]);
                acc[r][3] = fmaf(xs, w0.w, acc[r][3]);
                acc[r][4] = fmaf(xs, w1.x, acc[r][4]);
                acc[r][5] = fmaf(xs, w1.y, acc[r][5]);
                acc[r][6] = fmaf(xs, w1.z, acc[r][6]);
                acc[r][7] = fmaf(xs, w1.w, acc[r][7]);
            }
        }
        #pragma unroll
        for (int r = 0; r < 4; ++r) { xa[r] = na[r]; xb[r] = nb[r]; }
    }

    #pragma unroll
    for (int r = 0; r < 4; ++r) {
        if (rows[r] < n) {
            float a[8];
            #pragma unroll
            for (int c = 0; c < 8; ++c) {
                float v = acc[r][c];
                a[c] = v > 0.0f ? v : 0.01f * v;          // leaky_relu
            }
            #pragma unroll
            for (int rep = 0; rep < 2; ++rep) {           // reference normalizes twice
                float ss = 0.0f;
                #pragma unroll
                for (int d = 0; d < 8; ++d) ss = fmaf(a[d], a[d], ss);
                float inv = 1.0f / fmaxf(sqrtf(ss), 1e-12f);
                #pragma unroll
                for (int d = 0; d < 8; ++d) a[d] *= inv;
            }
            float* hr = h + (size_t)rows[r] * OUT_D + c0;
            float4 o1, o2;
            o1.x=a[0]; o1.y=a[1]; o1.z=a[2]; o1.w=a[3];
            o2.x=a[4]; o2.y=a[5]; o2.z=a[6]; o2.w=a[7];
            *(float4*)hr = o1;
            *(float4*)(hr + 4) = o2;
        }
    }
}

// ---------------- CSR build: two-level counting sort, 32-bit packed records ----
// pack = (local_trg << 16) | src   (src < n <= 65536, local_trg < 128)

__global__ __launch_bounds__(256) void bucket_hist_kernel(
    const int* __restrict__ trg, int m4, int* __restrict__ bucket_counts, int nb)
{
    __shared__ int hist[NBMAX];
    for (int i = threadIdx.x; i < nb; i += 256) hist[i] = 0;
    __syncthreads();
    int i = blockIdx.x * 256 + threadIdx.x;
    if (i < m4) {
        int4 t = ((const int4*)trg)[i];
        atomicAdd(&hist[t.x >> BSH], 1);
        atomicAdd(&hist[t.y >> BSH], 1);
        atomicAdd(&hist[t.z >> BSH], 1);
        atomicAdd(&hist[t.w >> BSH], 1);
    }
    __syncthreads();
    for (int i2 = threadIdx.x; i2 < nb; i2 += 256) {
        int c = hist[i2];
        if (c) atomicAdd(&bucket_counts[i2], c);
    }
}

__global__ __launch_bounds__(64) void bucket_scan_kernel(
    const int* __restrict__ bucket_counts, int* __restrict__ bucket_base,
    int* __restrict__ bucket_cursor, int nb, int n, int m, int* __restrict__ row_start)
{
    int lane = threadIdx.x;
    int carry = 0;
    for (int base = 0; base <= nb; base += 64) {
        int i = base + lane;
        int v = (i < nb) ? bucket_counts[i] : 0;
        int s = v;
        #pragma unroll
        for (int off = 1; off < 64; off <<= 1) {
            int t = __shfl_up(s, off, 64);
            if (lane >= off) s += t;
        }
        if (i <= nb) {
            int exc = carry + s - v;
            bucket_base[i]   = exc;
            bucket_cursor[i] = exc;
        }
        carry += __shfl(s, 63, 64);
    }
    if (lane == 0) row_start[n] = m;
}

// 8192 edges/block: LDS hist -> claim runs (1 atomic per block-bucket, runs ~21
// edges = dense lines) -> write packed 32-bit records (re-reads trg/src from L2)
__global__ __launch_bounds__(256) void partition_kernel(
    const int* __restrict__ trg, const int* __restrict__ src, int m4,
    uint32_t* __restrict__ epack, int* __restrict__ bucket_cursor, int nb)
{
    __shared__ int hist[NBMAX];
    __shared__ int runbase[NBMAX];
    for (int i = threadIdx.x; i < nb; i += 256) hist[i] = 0;
    __syncthreads();
    int base4 = blockIdx.x * 2048;   // 2048 int4 = 8192 edges
    #pragma unroll
    for (int j = 0; j < 8; ++j) {
        int i4 = base4 + j * 256 + threadIdx.x;
        if (i4 < m4) {
            int4 t = ((const int4*)trg)[i4];
            atomicAdd(&hist[t.x >> BSH], 1);
            atomicAdd(&hist[t.y >> BSH], 1);
            atomicAdd(&hist[t.z >> BSH], 1);
            atomicAdd(&hist[t.w >> BSH], 1);
        }
    }
    __syncthreads();
    for (int i = threadIdx.x; i < nb; i += 256) {
        int c = hist[i];
        runbase[i] = c ? atomicAdd(&bucket_cursor[i], c) : 0;
    }
    __syncthreads();
    for (int i = threadIdx.x; i < nb; i += 256) hist[i] = 0;   // reuse as local cursor
    __syncthreads();
    #pragma unroll
    for (int j = 0; j < 8; ++j) {
        int i4 = base4 + j * 256 + threadIdx.x;
        if (i4 < m4) {
            int4 t = ((const int4*)trg)[i4];
            int4 s = ((const int4*)src)[i4];
            int tt[4] = {t.x, t.y, t.z, t.w};
            int ss[4] = {s.x, s.y, s.z, s.w};
            #pragma unroll
            for (int q = 0; q < 4; ++q) {
                int b = tt[q] >> BSH;
                int r = atomicAdd(&hist[b], 1);
                epack[runbase[b] + r] =
                    ((uint32_t)(tt[q] & ((1 << BSH) - 1)) << 16) | (uint32_t)ss[q];
            }
        }
    }
}

// block per bucket: hist over 128 nodes -> rowstart + dense local scatter
__global__ __launch_bounds__(256) void local_csr_kernel(
    const uint32_t* __restrict__ epack, const int* __restrict__ bucket_base,
    int* __restrict__ row_start, int* __restrict__ edge_src, int n)
{
    __shared__ int hist[128];
    __shared__ int excl[129];
    __shared__ int cursor[128];
    int b = blockIdx.x;
    int ebeg = bucket_base[b], eend = bucket_base[b + 1];
    int node0 = b << BSH;
    if (threadIdx.x < 128) hist[threadIdx.x] = 0;
    __syncthreads();
    for (int e = ebeg + (int)threadIdx.x; e < eend; e += 256)
        atomicAdd(&hist[epack[e] >> 16], 1);
    __syncthreads();
    if (threadIdx.x < 64) {                       // wave 0: scan 128 counters
        int lane = threadIdx.x;
        int carry = 0;
        #pragma unroll
        for (int c = 0; c < 2; ++c) {
            int i = c * 64 + lane;
            int v = hist[i];
            int s = v;
            #pragma unroll
            for (int off = 1; off < 64; off <<= 1) {
                int t = __shfl_up(s, off, 64);
                if (lane >= off) s += t;
            }
            excl[i] = carry + s - v;
            carry += __shfl(s, 63, 64);
        }
        if (lane == 0) excl[128] = carry;
    }
    __syncthreads();
    int nh = n - node0; if (nh > 128) nh = 128;   // nodes in this bucket
    for (int i = threadIdx.x; i <= nh; i += 256)
        row_start[node0 + i] = ebeg + excl[i];
    if (threadIdx.x < 128) cursor[threadIdx.x] = excl[threadIdx.x];
    __syncthreads();
    for (int e = ebeg + (int)threadIdx.x; e < eend; e += 256) {
        uint32_t p = epack[e];
        int r = atomicAdd(&cursor[p >> 16], 1);
        edge_src[ebeg + r] = (int)(p & 0xFFFFu);  // dense 16KB L2-local region
    }
}

// ---------------- routing: wave per node, z in registers, LDS-free ----------------
// lane mapping: capsule k = lane bits {0,1,3}; edge-in-octet eo = lane bits {2,4,5}.
// c_sc = c * log2(e) folded once per iteration -> single v_exp per group.
__device__ __forceinline__ void route_group(const float z[8], const float csc[8], float acc[8]) {
    float p = z[0] * csc[0];
    #pragma unroll
    for (int d = 1; d < 8; ++d) p = fmaf(z[d], csc[d], p);
    float ex = exp2f(p);                // = exp(z.c), TAU = 1; |z.c|<=1 -> safe
    float sm = dpp_add_xor1(ex);
    sm = dpp_add_xor2(sm);
    sm = dpp_add_xor8(sm);
    float wgt = __fdividef(ex, sm);
    #pragma unroll
    for (int d = 0; d < 8; ++d) acc[d] = fmaf(wgt, z[d], acc[d]);
}

__global__ __launch_bounds__(256, 4) void route_kernel(
    const float* __restrict__ h, const int* __restrict__ row_start,
    const int* __restrict__ edge_src, float* __restrict__ out, int n)
{
    int lane = threadIdx.x & 63;
    int wid  = threadIdx.x >> 6;
    int v = blockIdx.x * 4 + wid;
    if (v >= n) return;
    int beg = row_start[v];
    int deg = row_start[v + 1] - beg;
    int nl  = deg < LCAP ? deg : LCAP;
    int ngroups = (nl + 7) >> 3;

    int k  = (lane & 3) | ((lane >> 1) & 4);         // capsule: lane bits 0,1,3
    int eo = ((lane >> 2) & 1) | ((lane >> 3) & 6);  // edge-octet: lane bits 2,4,5

    float c[8];
    load8v(c, h + (size_t)v * OUT_D + k * 8);

    float z[NG][8];
    #pragma unroll
    for (int g = 0; g < NG; ++g) {
        int e = g * 8 + eo;
        if (e < nl) {
            int s = edge_src[beg + e];
            load8v(z[g], h + (size_t)s * OUT_D + k * 8);
        } else {
            #pragma unroll
            for (int d = 0; d < 8; ++d) z[g][d] = 0.0f;
        }
    }

    #pragma unroll
    for (int it = 0; it < ROUTIT; ++it) {
        float csc[8];
        #pragma unroll
        for (int d = 0; d < 8; ++d) csc[d] = c[d] * LOG2E;
        float acc[8] = {0,0,0,0,0,0,0,0};
        #pragma unroll
        for (int g = 0; g < NG; ++g)
            if (g < ngroups) route_group(z[g], csc, acc);
        if (deg > LCAP) {
            for (int e0 = LCAP; e0 < deg; e0 += 8) {
                int e = e0 + eo;
                float zt[8] = {0,0,0,0,0,0,0,0};
                if (e < deg) {
                    int s = edge_src[beg + e];
                    load8v(zt, h + (size_t)s * OUT_D + k * 8);
                }
                route_group(zt, csc, acc);
            }
        }
        float ss = 0.0f;
        #pragma unroll
        for (int d = 0; d < 8; ++d) {
            float a = acc[d];
            a = swz_add_xor4(a);
            a = swz_add_xor16(a);
            a += __shfl_xor(a, 32, 64);
            float cv = c[d] + a;
            c[d] = cv;
            ss = fmaf(cv, cv, ss);
        }
        float inv = 1.0f / fmaxf(sqrtf(ss), 1e-12f);
        #pragma unroll
        for (int d = 0; d < 8; ++d) c[d] *= inv;
    }
    if (eo == 0) {
        float* op = out + (size_t)v * OUT_D + k * 8;
        float4 o1, o2;
        o1.x=c[0]; o1.y=c[1]; o1.z=c[2]; o1.w=c[3];
        o2.x=c[4]; o2.y=c[5]; o2.z=c[6]; o2.w=c[7];
        *(float4*)op = o1;
        *(float4*)(op + 4) = o2;
    }
}

// ---------------- launch ----------------
extern "C" void kernel_launch(void* const* d_in, const int* in_sizes, int n_in,
                              void* d_out, int out_size, void* d_ws, size_t ws_size,
                              hipStream_t stream)
{
    const float* x       = (const float*)d_in[0];
    const int*   src_trg = (const int*)d_in[1];
    const float* w       = (const float*)d_in[2];
    const float* bias    = (const float*)d_in[3];
    float*       out     = (float*)d_out;

    int n = in_sizes[0] / IN_DIM;   // 50000
    int m = in_sizes[1] / 2;        // 1638400
    int m4 = m >> 2;
    int nb = (n + 127) >> BSH;      // 391 buckets
    const int* trg = src_trg;       // row 0 = trg
    const int* src = src_trg + m;   // row 1 = src

    char* wsb = (char*)d_ws;
    size_t off = 0;
    float*    h        = (float*)(wsb + off);    off += (size_t)n * OUT_D * sizeof(float);
    int*      rowstart = (int*)(wsb + off);      off += (size_t)(n + 1) * sizeof(int);
    off = (off + 255) & ~(size_t)255;
    int*      edgesrc  = (int*)(wsb + off);      off += (size_t)m * sizeof(int);
    off = (off + 255) & ~(size_t)255;
    uint32_t* epack    = (uint32_t*)(wsb + off); off += (size_t)m * sizeof(uint32_t);
    int*      bcounts  = (int*)(wsb + off);      off += (size_t)(nb + 1) * sizeof(int);
    int*      bbase    = (int*)(wsb + off);      off += (size_t)(nb + 1) * sizeof(int);
    int*      bcursor  = (int*)(wsb + off);      off += (size_t)(nb + 1) * sizeof(int);

    hipMemsetAsync(bcounts, 0, (size_t)(nb + 1) * sizeof(int), stream);
    gemm_norm_kernel<<<(n + 255) / 256, 512, 0, stream>>>(x, w, bias, h, n);
    bucket_hist_kernel<<<(m4 + 255) / 256, 256, 0, stream>>>(trg, m4, bcounts, nb);
    bucket_scan_kernel<<<1, 64, 0, stream>>>(bcounts, bbase, bcursor, nb, n, m, rowstart);
    partition_kernel<<<(m4 + 2047) / 2048, 256, 0, stream>>>(trg, src, m4, epack, bcursor, nb);
    local_csr_kernel<<<nb, 256, 0, stream>>>(epack, bbase, rowstart, edgesrc, n);
    route_kernel<<<(n + 3) / 4, 256, 0, stream>>>(h, rowstart, edgesrc, out, n);
}

// Round 7
// 286.538 us; speedup vs baseline: 1.1115x; 1.1115x over previous
//
#include <hip/hip_runtime.h>
#include <math.h>
#include <stdint.h>

#define IN_DIM 256
#define OUT_D 64
#define ROUTIT 4
#define LCAP 48      // register-cached edges per node (6 groups of 8)
#define NG 6         // LCAP/8 fully-unrolled z-register groups
#define BSH 7        // bucket shift: 128 nodes per bucket
#define NBMAX 512    // supports n up to 65536 (packing needs n <= 65536 too)

// ---- cross-lane helpers ----
__device__ __forceinline__ float dpp_add_xor1(float x) {
    return x + __int_as_float(__builtin_amdgcn_mov_dpp(__float_as_int(x), 0xB1, 0xF, 0xF, true));
}
__device__ __forceinline__ float dpp_add_xor2(float x) {
    return x + __int_as_float(__builtin_amdgcn_mov_dpp(__float_as_int(x), 0x4E, 0xF, 0xF, true));
}
__device__ __forceinline__ float dpp_add_xor8(float x) {
    return x + __int_as_float(__builtin_amdgcn_mov_dpp(__float_as_int(x), 0x128, 0xF, 0xF, true));
}
__device__ __forceinline__ float swz_add_xor4(float x) {
    return x + __int_as_float(__builtin_amdgcn_ds_swizzle(__float_as_int(x), 0x101F));
}
__device__ __forceinline__ float swz_add_xor16(float x) {
    return x + __int_as_float(__builtin_amdgcn_ds_swizzle(__float_as_int(x), 0x401F));
}

__device__ __forceinline__ void load8v(float z[8], const float* p) {
    float4 a = *(const float4*)p;
    float4 b = *(const float4*)(p + 4);
    z[0]=a.x; z[1]=a.y; z[2]=a.z; z[3]=a.w;
    z[4]=b.x; z[5]=b.y; z[6]=b.z; z[7]=b.w;
}

// ---------------- h = l2norm(l2norm(leaky_relu(x @ W + b))) ----------------
// 4 rows/lane: each wave-uniform ds_read_b128 broadcast feeds 4 rows of FMAs.
__global__ __launch_bounds__(512, 2) void gemm_norm_kernel(
    const float* __restrict__ x, const float* __restrict__ w,
    const float* __restrict__ bias, float* __restrict__ h, int n)
{
    __shared__ float wlds[IN_DIM * OUT_D];   // 64 KB
    {
        const float4* wsrc = (const float4*)w;
        float4* wdst = (float4*)wlds;
        #pragma unroll
        for (int i = 0; i < (IN_DIM * OUT_D / 4); i += 512)
            wdst[i + threadIdx.x] = wsrc[i + threadIdx.x];
    }
    __syncthreads();

    int lane = threadIdx.x & 63;
    int wv   = threadIdx.x >> 6;          // 0..7
    int c0   = wv * 8;                    // this wave's capsule
    int base = blockIdx.x * 256;

    const float* xr[4];
    int rows[4];
    #pragma unroll
    for (int r = 0; r < 4; ++r) {
        rows[r] = base + r * 64 + lane;
        int rc = rows[r] < n ? rows[r] : n - 1;
        xr[r] = x + (size_t)rc * IN_DIM;
    }

    float acc[4][8];
    #pragma unroll
    for (int r = 0; r < 4; ++r)
        #pragma unroll
        for (int c = 0; c < 8; ++c) acc[r][c] = bias[c0 + c];

    float4 xa[4], xb[4];
    #pragma unroll
    for (int r = 0; r < 4; ++r) {
        xa[r] = *(const float4*)(xr[r]);
        xb[r] = *(const float4*)(xr[r] + 4);
    }

    for (int k0 = 0; k0 < IN_DIM; k0 += 8) {
        int kn = (k0 + 8 < IN_DIM) ? k0 + 8 : 0;       // wrap: harmless re-read
        float4 na[4], nb[4];
        #pragma unroll
        for (int r = 0; r < 4; ++r) {
            na[r] = *(const float4*)(xr[r] + kn);
            nb[r] = *(const float4*)(xr[r] + kn + 4);
        }
        const float* wk = wlds + k0 * OUT_D + c0;
        #pragma unroll
        for (int kk = 0; kk < 8; ++kk) {
            float4 w0 = *(const float4*)(wk + kk * OUT_D);      // broadcast b128
            float4 w1 = *(const float4*)(wk + kk * OUT_D + 4);
            #pragma unroll
            for (int r = 0; r < 4; ++r) {
                float xs = (kk < 4)
                    ? ((kk == 0) ? xa[r].x : (kk == 1) ? xa[r].y : (kk == 2) ? xa[r].z : xa[r].w)
                    : ((kk == 4) ? xb[r].x : (kk == 5) ? xb[r].y : (kk == 6) ? xb[r].z : xb[r].w);
                acc[r][0] = fmaf(xs, w0.x, acc[r][0]);
                acc[r][1] = fmaf(xs, w0.y, acc[r][1]);
                acc[r][2] = fmaf(xs, w0.z, acc[r][2]);
                acc[r][3] = fmaf(xs, w0.w, acc[r][3]);
                acc[r][4] = fmaf(xs, w1.x, acc[r][4]);
                acc[r][5] = fmaf(xs, w1.y, acc[r][5]);
                acc[r][6] = fmaf(xs, w1.z, acc[r][6]);
                acc[r][7] = fmaf(xs, w1.w, acc[r][7]);
            }
        }
        #pragma unroll
        for (int r = 0; r < 4; ++r) { xa[r] = na[r]; xb[r] = nb[r]; }
    }

    #pragma unroll
    for (int r = 0; r < 4; ++r) {
        if (rows[r] < n) {
            float a[8];
            #pragma unroll
            for (int c = 0; c < 8; ++c) {
                float v = acc[r][c];
                a[c] = v > 0.0f ? v : 0.01f * v;          // leaky_relu
            }
            #pragma unroll
            for (int rep = 0; rep < 2; ++rep) {           // reference normalizes twice
                float ss = 0.0f;
                #pragma unroll
                for (int d = 0; d < 8; ++d) ss = fmaf(a[d], a[d], ss);
                float inv = 1.0f / fmaxf(sqrtf(ss), 1e-12f);
                #pragma unroll
                for (int d = 0; d < 8; ++d) a[d] *= inv;
            }
            float* hr = h + (size_t)rows[r] * OUT_D + c0;
            float4 o1, o2;
            o1.x=a[0]; o1.y=a[1]; o1.z=a[2]; o1.w=a[3];
            o2.x=a[4]; o2.y=a[5]; o2.z=a[6]; o2.w=a[7];
            *(float4*)hr = o1;
            *(float4*)(hr + 4) = o2;
        }
    }
}

// ---------------- CSR build: two-level counting sort, 32-bit packed records ----
// pack = (local_trg << 16) | src   (src < n <= 65536, local_trg < 128)

// grid-stride, FIXED 256 blocks: one LDS-hist flush per block -> ~100K global
// atomics on the 391 bucket counters instead of 6400 blocks' ~2.2M (the R6
// hidden tail cost: same-address atomic serialization at L2).
__global__ __launch_bounds__(256) void bucket_hist_kernel(
    const int* __restrict__ trg, int m4, int* __restrict__ bucket_counts, int nb)
{
    __shared__ int hist[NBMAX];
    for (int i = threadIdx.x; i < nb; i += 256) hist[i] = 0;
    __syncthreads();
    for (int i = blockIdx.x * 256 + threadIdx.x; i < m4; i += 256 * gridDim.x) {
        int4 t = ((const int4*)trg)[i];
        atomicAdd(&hist[t.x >> BSH], 1);
        atomicAdd(&hist[t.y >> BSH], 1);
        atomicAdd(&hist[t.z >> BSH], 1);
        atomicAdd(&hist[t.w >> BSH], 1);
    }
    __syncthreads();
    for (int i = threadIdx.x; i < nb; i += 256) {
        int c = hist[i];
        if (c) atomicAdd(&bucket_counts[i], c);
    }
}

__global__ __launch_bounds__(64) void bucket_scan_kernel(
    const int* __restrict__ bucket_counts, int* __restrict__ bucket_base,
    int* __restrict__ bucket_cursor, int nb, int n, int m, int* __restrict__ row_start)
{
    int lane = threadIdx.x;
    int carry = 0;
    for (int base = 0; base <= nb; base += 64) {
        int i = base + lane;
        int v = (i < nb) ? bucket_counts[i] : 0;
        int s = v;
        #pragma unroll
        for (int off = 1; off < 64; off <<= 1) {
            int t = __shfl_up(s, off, 64);
            if (lane >= off) s += t;
        }
        if (i <= nb) {
            int exc = carry + s - v;
            bucket_base[i]   = exc;
            bucket_cursor[i] = exc;
        }
        carry += __shfl(s, 63, 64);
    }
    if (lane == 0) row_start[n] = m;
}

// 8192 edges/block: LDS hist -> claim runs (1 atomic per block-bucket) -> write packed
__global__ __launch_bounds__(256) void partition_kernel(
    const int* __restrict__ trg, const int* __restrict__ src, int m4,
    uint32_t* __restrict__ epack, int* __restrict__ bucket_cursor, int nb)
{
    __shared__ int hist[NBMAX];
    __shared__ int runbase[NBMAX];
    for (int i = threadIdx.x; i < nb; i += 256) hist[i] = 0;
    __syncthreads();
    int base4 = blockIdx.x * 2048;   // 2048 int4 = 8192 edges
    #pragma unroll
    for (int j = 0; j < 8; ++j) {
        int i4 = base4 + j * 256 + threadIdx.x;
        if (i4 < m4) {
            int4 t = ((const int4*)trg)[i4];
            atomicAdd(&hist[t.x >> BSH], 1);
            atomicAdd(&hist[t.y >> BSH], 1);
            atomicAdd(&hist[t.z >> BSH], 1);
            atomicAdd(&hist[t.w >> BSH], 1);
        }
    }
    __syncthreads();
    for (int i = threadIdx.x; i < nb; i += 256) {
        int c = hist[i];
        runbase[i] = c ? atomicAdd(&bucket_cursor[i], c) : 0;
    }
    __syncthreads();
    for (int i = threadIdx.x; i < nb; i += 256) hist[i] = 0;   // reuse as local cursor
    __syncthreads();
    #pragma unroll
    for (int j = 0; j < 8; ++j) {
        int i4 = base4 + j * 256 + threadIdx.x;
        if (i4 < m4) {
            int4 t = ((const int4*)trg)[i4];
            int4 s = ((const int4*)src)[i4];
            int tt[4] = {t.x, t.y, t.z, t.w};
            int ss[4] = {s.x, s.y, s.z, s.w};
            #pragma unroll
            for (int q = 0; q < 4; ++q) {
                int b = tt[q] >> BSH;
                int r = atomicAdd(&hist[b], 1);
                epack[runbase[b] + r] =
                    ((uint32_t)(tt[q] & ((1 << BSH) - 1)) << 16) | (uint32_t)ss[q];
            }
        }
    }
}

// block per bucket: hist over 128 nodes -> rowstart + dense local scatter
__global__ __launch_bounds__(256) void local_csr_kernel(
    const uint32_t* __restrict__ epack, const int* __restrict__ bucket_base,
    int* __restrict__ row_start, int* __restrict__ edge_src, int n)
{
    __shared__ int hist[128];
    __shared__ int excl[129];
    __shared__ int cursor[128];
    int b = blockIdx.x;
    int ebeg = bucket_base[b], eend = bucket_base[b + 1];
    int node0 = b << BSH;
    if (threadIdx.x < 128) hist[threadIdx.x] = 0;
    __syncthreads();
    for (int e = ebeg + (int)threadIdx.x; e < eend; e += 256)
        atomicAdd(&hist[epack[e] >> 16], 1);
    __syncthreads();
    if (threadIdx.x < 64) {                       // wave 0: scan 128 counters
        int lane = threadIdx.x;
        int carry = 0;
        #pragma unroll
        for (int c = 0; c < 2; ++c) {
            int i = c * 64 + lane;
            int v = hist[i];
            int s = v;
            #pragma unroll
            for (int off = 1; off < 64; off <<= 1) {
                int t = __shfl_up(s, off, 64);
                if (lane >= off) s += t;
            }
            excl[i] = carry + s - v;
            carry += __shfl(s, 63, 64);
        }
        if (lane == 0) excl[128] = carry;
    }
    __syncthreads();
    int nh = n - node0; if (nh > 128) nh = 128;   // nodes in this bucket
    for (int i = threadIdx.x; i <= nh; i += 256)
        row_start[node0 + i] = ebeg + excl[i];
    if (threadIdx.x < 128) cursor[threadIdx.x] = excl[threadIdx.x];
    __syncthreads();
    for (int e = ebeg + (int)threadIdx.x; e < eend; e += 256) {
        uint32_t p = epack[e];
        int r = atomicAdd(&cursor[p >> 16], 1);
        edge_src[ebeg + r] = (int)(p & 0xFFFFu);  // dense 16KB L2-local region
    }
}

// ---------------- routing: wave per node, z in registers, LDS-free ----------------
// lane mapping: capsule k = lane bits {0,1,3}; edge-in-octet eo = lane bits {2,4,5}.
// Per-edge softmax reduction (over k) = xor1/xor2/xor8 -> all DPP, zero DS ops.
// |p| <= 1 (unit-norm capsules) -> exp without max-subtract is safe.
// Zero-padded edge contributes exactly 0 to acc.
__device__ __forceinline__ void route_group(const float z[8], const float c[8], float acc[8]) {
    float p = z[0] * c[0];
    #pragma unroll
    for (int d = 1; d < 8; ++d) p = fmaf(z[d], c[d], p);
    float ex = __expf(p);               // TAU = 1
    float sm = dpp_add_xor1(ex);
    sm = dpp_add_xor2(sm);
    sm = dpp_add_xor8(sm);
    float wgt = __fdividef(ex, sm);
    #pragma unroll
    for (int d = 0; d < 8; ++d) acc[d] = fmaf(wgt, z[d], acc[d]);
}

__global__ __launch_bounds__(256, 4) void route_kernel(
    const float* __restrict__ h, const int* __restrict__ row_start,
    const int* __restrict__ edge_src, float* __restrict__ out, int n)
{
    int lane = threadIdx.x & 63;
    int wid  = threadIdx.x >> 6;
    int v = blockIdx.x * 4 + wid;
    if (v >= n) return;
    int beg = row_start[v];
    int deg = row_start[v + 1] - beg;
    int nl  = deg < LCAP ? deg : LCAP;
    int ngroups = (nl + 7) >> 3;

    int k  = (lane & 3) | ((lane >> 1) & 4);         // capsule: lane bits 0,1,3
    int eo = ((lane >> 2) & 1) | ((lane >> 3) & 6);  // edge-octet: lane bits 2,4,5

    float c[8];
    load8v(c, h + (size_t)v * OUT_D + k * 8);

    float z[NG][8];
    #pragma unroll
    for (int g = 0; g < NG; ++g) {
        int e = g * 8 + eo;
        if (e < nl) {
            int s = edge_src[beg + e];
            load8v(z[g], h + (size_t)s * OUT_D + k * 8);
        } else {
            #pragma unroll
            for (int d = 0; d < 8; ++d) z[g][d] = 0.0f;
        }
    }

    #pragma unroll
    for (int it = 0; it < ROUTIT; ++it) {
        float acc[8] = {0,0,0,0,0,0,0,0};
        #pragma unroll
        for (int g = 0; g < NG; ++g)
            if (g < ngroups) route_group(z[g], c, acc);
        if (deg > LCAP) {
            for (int e0 = LCAP; e0 < deg; e0 += 8) {
                int e = e0 + eo;
                float zt[8] = {0,0,0,0,0,0,0,0};
                if (e < deg) {
                    int s = edge_src[beg + e];
                    load8v(zt, h + (size_t)s * OUT_D + k * 8);
                }
                route_group(zt, c, acc);
            }
        }
        float ss = 0.0f;
        #pragma unroll
        for (int d = 0; d < 8; ++d) {
            float a = acc[d];
            a = swz_add_xor4(a);
            a = swz_add_xor16(a);
            a += __shfl_xor(a, 32, 64);
            float cv = c[d] + a;
            c[d] = cv;
            ss = fmaf(cv, cv, ss);
        }
        float inv = 1.0f / fmaxf(sqrtf(ss), 1e-12f);
        #pragma unroll
        for (int d = 0; d < 8; ++d) c[d] *= inv;
    }
    if (eo == 0) {
        float* op = out + (size_t)v * OUT_D + k * 8;
        float4 o1, o2;
        o1.x=c[0]; o1.y=c[1]; o1.z=c[2]; o1.w=c[3];
        o2.x=c[4]; o2.y=c[5]; o2.z=c[6]; o2.w=c[7];
        *(float4*)op = o1;
        *(float4*)(op + 4) = o2;
    }
}

// ---------------- launch ----------------
extern "C" void kernel_launch(void* const* d_in, const int* in_sizes, int n_in,
                              void* d_out, int out_size, void* d_ws, size_t ws_size,
                              hipStream_t stream)
{
    const float* x       = (const float*)d_in[0];
    const int*   src_trg = (const int*)d_in[1];
    const float* w       = (const float*)d_in[2];
    const float* bias    = (const float*)d_in[3];
    float*       out     = (float*)d_out;

    int n = in_sizes[0] / IN_DIM;   // 50000
    int m = in_sizes[1] / 2;        // 1638400
    int m4 = m >> 2;
    int nb = (n + 127) >> BSH;      // 391 buckets
    const int* trg = src_trg;       // row 0 = trg
    const int* src = src_trg + m;   // row 1 = src

    char* wsb = (char*)d_ws;
    size_t off = 0;
    float*    h        = (float*)(wsb + off);    off += (size_t)n * OUT_D * sizeof(float);
    int*      rowstart = (int*)(wsb + off);      off += (size_t)(n + 1) * sizeof(int);
    off = (off + 255) & ~(size_t)255;
    int*      edgesrc  = (int*)(wsb + off);      off += (size_t)m * sizeof(int);
    off = (off + 255) & ~(size_t)255;
    uint32_t* epack    = (uint32_t*)(wsb + off); off += (size_t)m * sizeof(uint32_t);
    int*      bcounts  = (int*)(wsb + off);      off += (size_t)(nb + 1) * sizeof(int);
    int*      bbase    = (int*)(wsb + off);      off += (size_t)(nb + 1) * sizeof(int);
    int*      bcursor  = (int*)(wsb + off);      off += (size_t)(nb + 1) * sizeof(int);

    hipMemsetAsync(bcounts, 0, (size_t)(nb + 1) * sizeof(int), stream);
    gemm_norm_kernel<<<(n + 255) / 256, 512, 0, stream>>>(x, w, bias, h, n);
    bucket_hist_kernel<<<256, 256, 0, stream>>>(trg, m4, bcounts, nb);
    bucket_scan_kernel<<<1, 64, 0, stream>>>(bcounts, bbase, bcursor, nb, n, m, rowstart);
    partition_kernel<<<(m4 + 2047) / 2048, 256, 0, stream>>>(trg, src, m4, epack, bcursor, nb);
    local_csr_kernel<<<nb, 256, 0, stream>>>(epack, bbase, rowstart, edgesrc, n);
    route_kernel<<<(n + 3) / 4, 256, 0, stream>>>(h, rowstart, edgesrc, out, n);
}

// Round 8
// 280.393 us; speedup vs baseline: 1.1358x; 1.0219x over previous
//
#include <hip/hip_runtime.h>
#include <math.h>
#include <stdint.h>

#define IN_DIM 256
#define OUT_D 64
#define ROUTIT 4
#define LCAP 48      // register-cached edges per node (6 groups of 8)
#define NG 6         // LCAP/8 fully-unrolled z-register groups
#define BSH 7        // bucket shift: 128 nodes per bucket
#define NBMAX 512    // supports n up to 65536 (packing needs n <= 65536 too)

typedef float v2f __attribute__((ext_vector_type(2)));
__device__ __forceinline__ v2f pk_fma(v2f a, v2f b, v2f c) {
    return __builtin_elementwise_fma(a, b, c);   // -> v_pk_fma_f32
}

// ---- cross-lane helpers ----
__device__ __forceinline__ float dpp_add_xor1(float x) {
    return x + __int_as_float(__builtin_amdgcn_mov_dpp(__float_as_int(x), 0xB1, 0xF, 0xF, true));
}
__device__ __forceinline__ float dpp_add_xor2(float x) {
    return x + __int_as_float(__builtin_amdgcn_mov_dpp(__float_as_int(x), 0x4E, 0xF, 0xF, true));
}
__device__ __forceinline__ float dpp_add_xor8(float x) {
    return x + __int_as_float(__builtin_amdgcn_mov_dpp(__float_as_int(x), 0x128, 0xF, 0xF, true));
}
__device__ __forceinline__ float swz_add_xor4(float x) {
    return x + __int_as_float(__builtin_amdgcn_ds_swizzle(__float_as_int(x), 0x101F));
}
__device__ __forceinline__ float swz_add_xor16(float x) {
    return x + __int_as_float(__builtin_amdgcn_ds_swizzle(__float_as_int(x), 0x401F));
}

// load 8 contiguous floats as 4 packed pairs (two b128 loads)
__device__ __forceinline__ void load8p(v2f z[4], const float* p) {
    float4 a = *(const float4*)p;
    float4 b = *(const float4*)(p + 4);
    z[0] = (v2f){a.x, a.y}; z[1] = (v2f){a.z, a.w};
    z[2] = (v2f){b.x, b.y}; z[3] = (v2f){b.z, b.w};
}

// ---------------- h = l2norm(l2norm(leaky_relu(x @ W + b))) ----------------
// 4 rows/lane; w in LDS (wave-uniform b128 broadcasts); inner loop in v_pk_fma_f32.
__global__ __launch_bounds__(512, 2) void gemm_norm_kernel(
    const float* __restrict__ x, const float* __restrict__ w,
    const float* __restrict__ bias, float* __restrict__ h, int n)
{
    __shared__ float wlds[IN_DIM * OUT_D];   // 64 KB
    {
        const float4* wsrc = (const float4*)w;
        float4* wdst = (float4*)wlds;
        #pragma unroll
        for (int i = 0; i < (IN_DIM * OUT_D / 4); i += 512)
            wdst[i + threadIdx.x] = wsrc[i + threadIdx.x];
    }
    __syncthreads();

    int lane = threadIdx.x & 63;
    int wv   = threadIdx.x >> 6;          // 0..7
    int c0   = wv * 8;                    // this wave's capsule
    int base = blockIdx.x * 256;

    const float* xr[4];
    int rows[4];
    #pragma unroll
    for (int r = 0; r < 4; ++r) {
        rows[r] = base + r * 64 + lane;
        int rc = rows[r] < n ? rows[r] : n - 1;
        xr[r] = x + (size_t)rc * IN_DIM;
    }

    v2f b2[4];
    #pragma unroll
    for (int j = 0; j < 4; ++j) b2[j] = (v2f){bias[c0 + 2*j], bias[c0 + 2*j + 1]};
    v2f acc[4][4];
    #pragma unroll
    for (int r = 0; r < 4; ++r)
        #pragma unroll
        for (int j = 0; j < 4; ++j) acc[r][j] = b2[j];

    float4 xa[4], xb[4];
    #pragma unroll
    for (int r = 0; r < 4; ++r) {
        xa[r] = *(const float4*)(xr[r]);
        xb[r] = *(const float4*)(xr[r] + 4);
    }

    for (int k0 = 0; k0 < IN_DIM; k0 += 8) {
        int kn = (k0 + 8 < IN_DIM) ? k0 + 8 : 0;       // wrap: harmless re-read
        float4 na[4], nb[4];
        #pragma unroll
        for (int r = 0; r < 4; ++r) {
            na[r] = *(const float4*)(xr[r] + kn);
            nb[r] = *(const float4*)(xr[r] + kn + 4);
        }
        const float* wk = wlds + k0 * OUT_D + c0;
        #pragma unroll
        for (int kk = 0; kk < 8; ++kk) {
            float4 w0 = *(const float4*)(wk + kk * OUT_D);      // broadcast b128
            float4 w1 = *(const float4*)(wk + kk * OUT_D + 4);
            v2f wvp[4] = {{w0.x,w0.y},{w0.z,w0.w},{w1.x,w1.y},{w1.z,w1.w}};
            #pragma unroll
            for (int r = 0; r < 4; ++r) {
                float xs = (kk < 4)
                    ? ((kk == 0) ? xa[r].x : (kk == 1) ? xa[r].y : (kk == 2) ? xa[r].z : xa[r].w)
                    : ((kk == 4) ? xb[r].x : (kk == 5) ? xb[r].y : (kk == 6) ? xb[r].z : xb[r].w);
                v2f xs2 = (v2f){xs, xs};
                acc[r][0] = pk_fma(xs2, wvp[0], acc[r][0]);
                acc[r][1] = pk_fma(xs2, wvp[1], acc[r][1]);
                acc[r][2] = pk_fma(xs2, wvp[2], acc[r][2]);
                acc[r][3] = pk_fma(xs2, wvp[3], acc[r][3]);
            }
        }
        #pragma unroll
        for (int r = 0; r < 4; ++r) { xa[r] = na[r]; xb[r] = nb[r]; }
    }

    #pragma unroll
    for (int r = 0; r < 4; ++r) {
        if (rows[r] < n) {
            float a[8];
            #pragma unroll
            for (int j = 0; j < 4; ++j) { a[2*j] = acc[r][j][0]; a[2*j+1] = acc[r][j][1]; }
            #pragma unroll
            for (int c = 0; c < 8; ++c) a[c] = a[c] > 0.0f ? a[c] : 0.01f * a[c];  // leaky
            #pragma unroll
            for (int rep = 0; rep < 2; ++rep) {           // reference normalizes twice
                float ss = 0.0f;
                #pragma unroll
                for (int d = 0; d < 8; ++d) ss = fmaf(a[d], a[d], ss);
                float inv = 1.0f / fmaxf(sqrtf(ss), 1e-12f);
                #pragma unroll
                for (int d = 0; d < 8; ++d) a[d] *= inv;
            }
            float* hr = h + (size_t)rows[r] * OUT_D + c0;
            float4 o1, o2;
            o1.x=a[0]; o1.y=a[1]; o1.z=a[2]; o1.w=a[3];
            o2.x=a[4]; o2.y=a[5]; o2.z=a[6]; o2.w=a[7];
            *(float4*)hr = o1;
            *(float4*)(hr + 4) = o2;
        }
    }
}

// ---------------- CSR build: two-level counting sort, 32-bit packed records ----
// pack = (local_trg << 16) | src   (src < n <= 65536, local_trg < 128)

// grid-stride, fixed 256 blocks: one LDS-hist flush per block
__global__ __launch_bounds__(256) void bucket_hist_kernel(
    const int* __restrict__ trg, int m4, int* __restrict__ bucket_counts, int nb)
{
    __shared__ int hist[NBMAX];
    for (int i = threadIdx.x; i < nb; i += 256) hist[i] = 0;
    __syncthreads();
    for (int i = blockIdx.x * 256 + threadIdx.x; i < m4; i += 256 * gridDim.x) {
        int4 t = ((const int4*)trg)[i];
        atomicAdd(&hist[t.x >> BSH], 1);
        atomicAdd(&hist[t.y >> BSH], 1);
        atomicAdd(&hist[t.z >> BSH], 1);
        atomicAdd(&hist[t.w >> BSH], 1);
    }
    __syncthreads();
    for (int i = threadIdx.x; i < nb; i += 256) {
        int c = hist[i];
        if (c) atomicAdd(&bucket_counts[i], c);
    }
}

__global__ __launch_bounds__(64) void bucket_scan_kernel(
    const int* __restrict__ bucket_counts, int* __restrict__ bucket_base,
    int* __restrict__ bucket_cursor, int nb, int n, int m, int* __restrict__ row_start)
{
    int lane = threadIdx.x;
    int carry = 0;
    for (int base = 0; base <= nb; base += 64) {
        int i = base + lane;
        int v = (i < nb) ? bucket_counts[i] : 0;
        int s = v;
        #pragma unroll
        for (int off = 1; off < 64; off <<= 1) {
            int t = __shfl_up(s, off, 64);
            if (lane >= off) s += t;
        }
        if (i <= nb) {
            int exc = carry + s - v;
            bucket_base[i]   = exc;
            bucket_cursor[i] = exc;
        }
        carry += __shfl(s, 63, 64);
    }
    if (lane == 0) row_start[n] = m;
}

// 8192 edges/block, 1024 threads (16 waves: hide LDS-atomic latency chains)
__global__ __launch_bounds__(1024) void partition_kernel(
    const int* __restrict__ trg, const int* __restrict__ src, int m4,
    uint32_t* __restrict__ epack, int* __restrict__ bucket_cursor, int nb)
{
    __shared__ int hist[NBMAX];
    __shared__ int runbase[NBMAX];
    for (int i = threadIdx.x; i < nb; i += 1024) hist[i] = 0;
    __syncthreads();
    int base4 = blockIdx.x * 2048;   // 2048 int4 = 8192 edges
    #pragma unroll
    for (int j = 0; j < 2; ++j) {
        int i4 = base4 + j * 1024 + threadIdx.x;
        if (i4 < m4) {
            int4 t = ((const int4*)trg)[i4];
            atomicAdd(&hist[t.x >> BSH], 1);
            atomicAdd(&hist[t.y >> BSH], 1);
            atomicAdd(&hist[t.z >> BSH], 1);
            atomicAdd(&hist[t.w >> BSH], 1);
        }
    }
    __syncthreads();
    for (int i = threadIdx.x; i < nb; i += 1024) {
        int c = hist[i];
        runbase[i] = c ? atomicAdd(&bucket_cursor[i], c) : 0;
    }
    __syncthreads();
    for (int i = threadIdx.x; i < nb; i += 1024) hist[i] = 0;   // reuse as local cursor
    __syncthreads();
    #pragma unroll
    for (int j = 0; j < 2; ++j) {
        int i4 = base4 + j * 1024 + threadIdx.x;
        if (i4 < m4) {
            int4 t = ((const int4*)trg)[i4];
            int4 s = ((const int4*)src)[i4];
            int tt[4] = {t.x, t.y, t.z, t.w};
            int ss[4] = {s.x, s.y, s.z, s.w};
            #pragma unroll
            for (int q = 0; q < 4; ++q) {
                int b = tt[q] >> BSH;
                int r = atomicAdd(&hist[b], 1);
                epack[runbase[b] + r] =
                    ((uint32_t)(tt[q] & ((1 << BSH) - 1)) << 16) | (uint32_t)ss[q];
            }
        }
    }
}

// block per bucket, 512 threads: hist over 128 nodes -> rowstart + dense local scatter
__global__ __launch_bounds__(512) void local_csr_kernel(
    const uint32_t* __restrict__ epack, const int* __restrict__ bucket_base,
    int* __restrict__ row_start, int* __restrict__ edge_src, int n)
{
    __shared__ int hist[128];
    __shared__ int excl[129];
    __shared__ int cursor[128];
    int b = blockIdx.x;
    int ebeg = bucket_base[b], eend = bucket_base[b + 1];
    int node0 = b << BSH;
    if (threadIdx.x < 128) hist[threadIdx.x] = 0;
    __syncthreads();
    for (int e = ebeg + (int)threadIdx.x; e < eend; e += 512)
        atomicAdd(&hist[epack[e] >> 16], 1);
    __syncthreads();
    if (threadIdx.x < 64) {                       // wave 0: scan 128 counters
        int lane = threadIdx.x;
        int carry = 0;
        #pragma unroll
        for (int c = 0; c < 2; ++c) {
            int i = c * 64 + lane;
            int v = hist[i];
            int s = v;
            #pragma unroll
            for (int off = 1; off < 64; off <<= 1) {
                int t = __shfl_up(s, off, 64);
                if (lane >= off) s += t;
            }
            excl[i] = carry + s - v;
            carry += __shfl(s, 63, 64);
        }
        if (lane == 0) excl[128] = carry;
    }
    __syncthreads();
    int nh = n - node0; if (nh > 128) nh = 128;   // nodes in this bucket
    for (int i = threadIdx.x; i <= nh; i += 512)
        row_start[node0 + i] = ebeg + excl[i];
    if (threadIdx.x < 128) cursor[threadIdx.x] = excl[threadIdx.x];
    __syncthreads();
    for (int e = ebeg + (int)threadIdx.x; e < eend; e += 512) {
        uint32_t p = epack[e];
        int r = atomicAdd(&cursor[p >> 16], 1);
        edge_src[ebeg + r] = (int)(p & 0xFFFFu);  // dense 16KB L2-local region
    }
}

// ---------------- routing: wave per node, z in registers, LDS-free ----------------
// capsule k = lane bits {0,1,3}; edge-octet eo = lane bits {2,4,5}.
// Per-edge softmax reduction = xor1/xor2/xor8, all DPP (VALU pipe).
// dot & acc in v_pk_fma_f32 (2x fp32/inst). |p|<=1 -> no max-subtract needed.
__device__ __forceinline__ void route_group(const v2f z[4], const v2f c[4], v2f acc[4]) {
    v2f p2 = z[0] * c[0];
    p2 = pk_fma(z[1], c[1], p2);
    p2 = pk_fma(z[2], c[2], p2);
    p2 = pk_fma(z[3], c[3], p2);
    float p = p2[0] + p2[1];
    float ex = __expf(p);               // TAU = 1
    float sm = dpp_add_xor1(ex);
    sm = dpp_add_xor2(sm);
    sm = dpp_add_xor8(sm);
    float wgt = __fdividef(ex, sm);
    v2f w2 = (v2f){wgt, wgt};
    acc[0] = pk_fma(w2, z[0], acc[0]);
    acc[1] = pk_fma(w2, z[1], acc[1]);
    acc[2] = pk_fma(w2, z[2], acc[2]);
    acc[3] = pk_fma(w2, z[3], acc[3]);
}

__global__ __launch_bounds__(256, 4) void route_kernel(
    const float* __restrict__ h, const int* __restrict__ row_start,
    const int* __restrict__ edge_src, float* __restrict__ out, int n)
{
    int lane = threadIdx.x & 63;
    int wid  = threadIdx.x >> 6;
    int v = blockIdx.x * 4 + wid;
    if (v >= n) return;
    int beg = row_start[v];
    int deg = row_start[v + 1] - beg;
    int nl  = deg < LCAP ? deg : LCAP;
    int ngroups = (nl + 7) >> 3;

    int k  = (lane & 3) | ((lane >> 1) & 4);         // capsule: lane bits 0,1,3
    int eo = ((lane >> 2) & 1) | ((lane >> 3) & 6);  // edge-octet: lane bits 2,4,5

    v2f c[4];
    load8p(c, h + (size_t)v * OUT_D + k * 8);

    v2f z[NG][4];
    #pragma unroll
    for (int g = 0; g < NG; ++g) {
        int e = g * 8 + eo;
        if (e < nl) {
            int s = edge_src[beg + e];
            load8p(z[g], h + (size_t)s * OUT_D + k * 8);
        } else {
            #pragma unroll
            for (int d = 0; d < 4; ++d) z[g][d] = (v2f){0.0f, 0.0f};
        }
    }

    #pragma unroll
    for (int it = 0; it < ROUTIT; ++it) {
        v2f acc[4] = {{0,0},{0,0},{0,0},{0,0}};
        #pragma unroll
        for (int g = 0; g < NG; ++g)
            if (g < ngroups) route_group(z[g], c, acc);   // wave-uniform guard
        if (deg > LCAP) {
            for (int e0 = LCAP; e0 < deg; e0 += 8) {
                int e = e0 + eo;
                v2f zt[4] = {{0,0},{0,0},{0,0},{0,0}};
                if (e < deg) {
                    int s = edge_src[beg + e];
                    load8p(zt, h + (size_t)s * OUT_D + k * 8);
                }
                route_group(zt, c, acc);
            }
        }
        // reduce acc over the 8 edge-octets (lane bits 2,4,5); norm is in-lane
        float ss = 0.0f;
        #pragma unroll
        for (int d = 0; d < 8; ++d) {
            float a = acc[d >> 1][d & 1];
            a = swz_add_xor4(a);
            a = swz_add_xor16(a);
            a += __shfl_xor(a, 32, 64);
            float cv = c[d >> 1][d & 1] + a;
            c[d >> 1][d & 1] = cv;
            ss = fmaf(cv, cv, ss);
        }
        float inv = 1.0f / fmaxf(sqrtf(ss), 1e-12f);
        v2f inv2 = (v2f){inv, inv};
        #pragma unroll
        for (int j = 0; j < 4; ++j) c[j] *= inv2;
    }
    if (eo == 0) {                                   // lanes {0-3, 8-11} hold k=0..7
        float* op = out + (size_t)v * OUT_D + k * 8;
        float4 o1, o2;
        o1.x=c[0][0]; o1.y=c[0][1]; o1.z=c[1][0]; o1.w=c[1][1];
        o2.x=c[2][0]; o2.y=c[2][1]; o2.z=c[3][0]; o2.w=c[3][1];
        *(float4*)op = o1;
        *(float4*)(op + 4) = o2;
    }
}

// ---------------- launch ----------------
extern "C" void kernel_launch(void* const* d_in, const int* in_sizes, int n_in,
                              void* d_out, int out_size, void* d_ws, size_t ws_size,
                              hipStream_t stream)
{
    const float* x       = (const float*)d_in[0];
    const int*   src_trg = (const int*)d_in[1];
    const float* w       = (const float*)d_in[2];
    const float* bias    = (const float*)d_in[3];
    float*       out     = (float*)d_out;

    int n = in_sizes[0] / IN_DIM;   // 50000
    int m = in_sizes[1] / 2;        // 1638400
    int m4 = m >> 2;
    int nb = (n + 127) >> BSH;      // 391 buckets
    const int* trg = src_trg;       // row 0 = trg
    const int* src = src_trg + m;   // row 1 = src

    char* wsb = (char*)d_ws;
    size_t off = 0;
    float*    h        = (float*)(wsb + off);    off += (size_t)n * OUT_D * sizeof(float);
    int*      rowstart = (int*)(wsb + off);      off += (size_t)(n + 1) * sizeof(int);
    off = (off + 255) & ~(size_t)255;
    int*      edgesrc  = (int*)(wsb + off);      off += (size_t)m * sizeof(int);
    off = (off + 255) & ~(size_t)255;
    uint32_t* epack    = (uint32_t*)(wsb + off); off += (size_t)m * sizeof(uint32_t);
    int*      bcounts  = (int*)(wsb + off);      off += (size_t)(nb + 1) * sizeof(int);
    int*      bbase    = (int*)(wsb + off);      off += (size_t)(nb + 1) * sizeof(int);
    int*      bcursor  = (int*)(wsb + off);      off += (size_t)(nb + 1) * sizeof(int);

    hipMemsetAsync(bcounts, 0, (size_t)(nb + 1) * sizeof(int), stream);
    gemm_norm_kernel<<<(n + 255) / 256, 512, 0, stream>>>(x, w, bias, h, n);
    bucket_hist_kernel<<<256, 256, 0, stream>>>(trg, m4, bcounts, nb);
    bucket_scan_kernel<<<1, 64, 0, stream>>>(bcounts, bbase, bcursor, nb, n, m, rowstart);
    partition_kernel<<<(m4 + 2047) / 2048, 1024, 0, stream>>>(trg, src, m4, epack, bcursor, nb);
    local_csr_kernel<<<nb, 512, 0, stream>>>(epack, bbase, rowstart, edgesrc, n);
    route_kernel<<<(n + 3) / 4, 256, 0, stream>>>(h, rowstart, edgesrc, out, n);
}

// Round 9
// 273.242 us; speedup vs baseline: 1.1656x; 1.0262x over previous
//
#include <hip/hip_runtime.h>
#include <math.h>
#include <stdint.h>

#define IN_DIM 256
#define OUT_D 64
#define ROUTIT 4
#define LCAP 48      // register-cached edges per node (6 groups of 8)
#define NG 6         // LCAP/8 fully-unrolled z-register groups
#define BSH 7        // bucket shift: 128 nodes per bucket
#define NBMAX 512    // supports n up to 65536 (16-bit packing limit too)
#define PEDGES 8192  // partition: edges per block (32 KB LDS stage)
#define LCCAP 6144   // local_csr: sorted-stage capacity (bucket avg ~4194, +30 sigma)

typedef float v2f __attribute__((ext_vector_type(2)));
__device__ __forceinline__ v2f pk_fma(v2f a, v2f b, v2f c) {
    return __builtin_elementwise_fma(a, b, c);   // -> v_pk_fma_f32
}

// ---- cross-lane helpers ----
__device__ __forceinline__ float dpp_add_xor1(float x) {
    return x + __int_as_float(__builtin_amdgcn_mov_dpp(__float_as_int(x), 0xB1, 0xF, 0xF, true));
}
__device__ __forceinline__ float dpp_add_xor2(float x) {
    return x + __int_as_float(__builtin_amdgcn_mov_dpp(__float_as_int(x), 0x4E, 0xF, 0xF, true));
}
__device__ __forceinline__ float dpp_add_xor8(float x) {
    return x + __int_as_float(__builtin_amdgcn_mov_dpp(__float_as_int(x), 0x128, 0xF, 0xF, true));
}
__device__ __forceinline__ float swz_add_xor4(float x) {
    return x + __int_as_float(__builtin_amdgcn_ds_swizzle(__float_as_int(x), 0x101F));
}
__device__ __forceinline__ float swz_add_xor16(float x) {
    return x + __int_as_float(__builtin_amdgcn_ds_swizzle(__float_as_int(x), 0x401F));
}

__device__ __forceinline__ void load8p(v2f z[4], const float* p) {
    float4 a = *(const float4*)p;
    float4 b = *(const float4*)(p + 4);
    z[0] = (v2f){a.x, a.y}; z[1] = (v2f){a.z, a.w};
    z[2] = (v2f){b.x, b.y}; z[3] = (v2f){b.z, b.w};
}

// ---------------- h = l2norm(l2norm(leaky_relu(x @ W + b))) ----------------
__global__ __launch_bounds__(512, 2) void gemm_norm_kernel(
    const float* __restrict__ x, const float* __restrict__ w,
    const float* __restrict__ bias, float* __restrict__ h, int n)
{
    __shared__ float wlds[IN_DIM * OUT_D];   // 64 KB
    {
        const float4* wsrc = (const float4*)w;
        float4* wdst = (float4*)wlds;
        #pragma unroll
        for (int i = 0; i < (IN_DIM * OUT_D / 4); i += 512)
            wdst[i + threadIdx.x] = wsrc[i + threadIdx.x];
    }
    __syncthreads();

    int lane = threadIdx.x & 63;
    int wv   = threadIdx.x >> 6;          // 0..7
    int c0   = wv * 8;                    // this wave's capsule
    int base = blockIdx.x * 256;

    const float* xr[4];
    int rows[4];
    #pragma unroll
    for (int r = 0; r < 4; ++r) {
        rows[r] = base + r * 64 + lane;
        int rc = rows[r] < n ? rows[r] : n - 1;
        xr[r] = x + (size_t)rc * IN_DIM;
    }

    v2f b2[4];
    #pragma unroll
    for (int j = 0; j < 4; ++j) b2[j] = (v2f){bias[c0 + 2*j], bias[c0 + 2*j + 1]};
    v2f acc[4][4];
    #pragma unroll
    for (int r = 0; r < 4; ++r)
        #pragma unroll
        for (int j = 0; j < 4; ++j) acc[r][j] = b2[j];

    float4 xa[4], xb[4];
    #pragma unroll
    for (int r = 0; r < 4; ++r) {
        xa[r] = *(const float4*)(xr[r]);
        xb[r] = *(const float4*)(xr[r] + 4);
    }

    for (int k0 = 0; k0 < IN_DIM; k0 += 8) {
        int kn = (k0 + 8 < IN_DIM) ? k0 + 8 : 0;       // wrap: harmless re-read
        float4 na[4], nb[4];
        #pragma unroll
        for (int r = 0; r < 4; ++r) {
            na[r] = *(const float4*)(xr[r] + kn);
            nb[r] = *(const float4*)(xr[r] + kn + 4);
        }
        const float* wk = wlds + k0 * OUT_D + c0;
        #pragma unroll
        for (int kk = 0; kk < 8; ++kk) {
            float4 w0 = *(const float4*)(wk + kk * OUT_D);      // broadcast b128
            float4 w1 = *(const float4*)(wk + kk * OUT_D + 4);
            v2f wvp[4] = {{w0.x,w0.y},{w0.z,w0.w},{w1.x,w1.y},{w1.z,w1.w}};
            #pragma unroll
            for (int r = 0; r < 4; ++r) {
                float xs = (kk < 4)
                    ? ((kk == 0) ? xa[r].x : (kk == 1) ? xa[r].y : (kk == 2) ? xa[r].z : xa[r].w)
                    : ((kk == 4) ? xb[r].x : (kk == 5) ? xb[r].y : (kk == 6) ? xb[r].z : xb[r].w);
                v2f xs2 = (v2f){xs, xs};
                acc[r][0] = pk_fma(xs2, wvp[0], acc[r][0]);
                acc[r][1] = pk_fma(xs2, wvp[1], acc[r][1]);
                acc[r][2] = pk_fma(xs2, wvp[2], acc[r][2]);
                acc[r][3] = pk_fma(xs2, wvp[3], acc[r][3]);
            }
        }
        #pragma unroll
        for (int r = 0; r < 4; ++r) { xa[r] = na[r]; xb[r] = nb[r]; }
    }

    #pragma unroll
    for (int r = 0; r < 4; ++r) {
        if (rows[r] < n) {
            float a[8];
            #pragma unroll
            for (int j = 0; j < 4; ++j) { a[2*j] = acc[r][j][0]; a[2*j+1] = acc[r][j][1]; }
            #pragma unroll
            for (int c = 0; c < 8; ++c) a[c] = a[c] > 0.0f ? a[c] : 0.01f * a[c];  // leaky
            #pragma unroll
            for (int rep = 0; rep < 2; ++rep) {           // reference normalizes twice
                float ss = 0.0f;
                #pragma unroll
                for (int d = 0; d < 8; ++d) ss = fmaf(a[d], a[d], ss);
                float inv = 1.0f / fmaxf(sqrtf(ss), 1e-12f);
                #pragma unroll
                for (int d = 0; d < 8; ++d) a[d] *= inv;
            }
            float* hr = h + (size_t)rows[r] * OUT_D + c0;
            float4 o1, o2;
            o1.x=a[0]; o1.y=a[1]; o1.z=a[2]; o1.w=a[3];
            o2.x=a[4]; o2.y=a[5]; o2.z=a[6]; o2.w=a[7];
            *(float4*)hr = o1;
            *(float4*)(hr + 4) = o2;
        }
    }
}

// ---------------- CSR build: two-level counting sort ----------------
// record = (trg << 16) | src  (both < 65536); bucket = trg >> BSH = rec >> (16+BSH)

// grid-stride, fixed 256 blocks: one LDS-hist flush per block
__global__ __launch_bounds__(256) void bucket_hist_kernel(
    const int* __restrict__ trg, int m4, int* __restrict__ bucket_counts, int nb)
{
    __shared__ int hist[NBMAX];
    for (int i = threadIdx.x; i < nb; i += 256) hist[i] = 0;
    __syncthreads();
    for (int i = blockIdx.x * 256 + threadIdx.x; i < m4; i += 256 * gridDim.x) {
        int4 t = ((const int4*)trg)[i];
        atomicAdd(&hist[t.x >> BSH], 1);
        atomicAdd(&hist[t.y >> BSH], 1);
        atomicAdd(&hist[t.z >> BSH], 1);
        atomicAdd(&hist[t.w >> BSH], 1);
    }
    __syncthreads();
    for (int i = threadIdx.x; i < nb; i += 256) {
        int c = hist[i];
        if (c) atomicAdd(&bucket_counts[i], c);
    }
}

__global__ __launch_bounds__(64) void bucket_scan_kernel(
    const int* __restrict__ bucket_counts, int* __restrict__ bucket_base,
    int* __restrict__ bucket_cursor, int nb, int n, int m, int* __restrict__ row_start)
{
    int lane = threadIdx.x;
    int carry = 0;
    for (int base = 0; base <= nb; base += 64) {
        int i = base + lane;
        int v = (i < nb) ? bucket_counts[i] : 0;
        int s = v;
        #pragma unroll
        for (int off = 1; off < 64; off <<= 1) {
            int t = __shfl_up(s, off, 64);
            if (lane >= off) s += t;
        }
        if (i <= nb) {
            int exc = carry + s - v;
            bucket_base[i]   = exc;
            bucket_cursor[i] = exc;
        }
        carry += __shfl(s, 63, 64);
    }
    if (lane == 0) row_start[n] = m;
}

// partition v2: LDS-staged, ORDERED copy-out (coalesced global writes).
// 8192 edges/block, 1024 threads.
__global__ __launch_bounds__(1024) void partition_kernel(
    const int* __restrict__ trg, const int* __restrict__ src, int m4,
    uint32_t* __restrict__ epack, int* __restrict__ bucket_cursor, int nb)
{
    __shared__ uint32_t stage[PEDGES];   // 32 KB
    __shared__ int hist[NBMAX];
    __shared__ int lbase[NBMAX];
    __shared__ int gdelta[NBMAX];
    for (int i = threadIdx.x; i < nb; i += 1024) hist[i] = 0;
    __syncthreads();
    int base4 = blockIdx.x * (PEDGES / 4);
    // A: histogram
    #pragma unroll
    for (int j = 0; j < PEDGES / 4 / 1024; ++j) {
        int i4 = base4 + j * 1024 + threadIdx.x;
        if (i4 < m4) {
            int4 t = ((const int4*)trg)[i4];
            atomicAdd(&hist[t.x >> BSH], 1);
            atomicAdd(&hist[t.y >> BSH], 1);
            atomicAdd(&hist[t.z >> BSH], 1);
            atomicAdd(&hist[t.w >> BSH], 1);
        }
    }
    __syncthreads();
    // B: block-local exclusive scan of hist -> lbase (wave 0)
    if (threadIdx.x < 64) {
        int lane = threadIdx.x;
        int carry = 0;
        for (int b0 = 0; b0 < nb; b0 += 64) {
            int i = b0 + lane;
            int v = (i < nb) ? hist[i] : 0;
            int s = v;
            #pragma unroll
            for (int off = 1; off < 64; off <<= 1) {
                int t = __shfl_up(s, off, 64);
                if (lane >= off) s += t;
            }
            if (i < nb) lbase[i] = carry + s - v;
            carry += __shfl(s, 63, 64);
        }
    }
    __syncthreads();
    // claim global runs; gdelta maps stage index -> global index
    for (int i = threadIdx.x; i < nb; i += 1024) {
        int c = hist[i];
        int g = c ? atomicAdd(&bucket_cursor[i], c) : 0;
        gdelta[i] = g - lbase[i];
    }
    __syncthreads();
    for (int i = threadIdx.x; i < nb; i += 1024) hist[i] = 0;   // reuse as cursor
    __syncthreads();
    // C: scatter records into LDS stage (grouped by bucket)
    #pragma unroll
    for (int j = 0; j < PEDGES / 4 / 1024; ++j) {
        int i4 = base4 + j * 1024 + threadIdx.x;
        if (i4 < m4) {
            int4 t = ((const int4*)trg)[i4];
            int4 s = ((const int4*)src)[i4];
            int tt[4] = {t.x, t.y, t.z, t.w};
            int ss[4] = {s.x, s.y, s.z, s.w};
            #pragma unroll
            for (int q = 0; q < 4; ++q) {
                int b = tt[q] >> BSH;
                int r = atomicAdd(&hist[b], 1);
                stage[lbase[b] + r] = ((uint32_t)tt[q] << 16) | (uint32_t)ss[q];
            }
        }
    }
    __syncthreads();
    // D: ordered copy-out -- consecutive i within a bucket -> consecutive addrs
    int rem = (m4 - base4) * 4;
    int cnt = rem < PEDGES ? rem : PEDGES;
    for (int i = threadIdx.x; i < cnt; i += 1024) {
        uint32_t p = stage[i];
        int b = (int)(p >> (16 + BSH));
        epack[gdelta[b] + i] = p;
    }
}

// local_csr v2: sort bucket into LDS, then one dense coalesced write.
__global__ __launch_bounds__(512) void local_csr_kernel(
    const uint32_t* __restrict__ epack, const int* __restrict__ bucket_base,
    int* __restrict__ row_start, int* __restrict__ edge_src, int n)
{
    __shared__ int sorted[LCCAP];   // 24 KB
    __shared__ int hist[128];
    __shared__ int excl[129];
    __shared__ int cursor[128];
    int b = blockIdx.x;
    int ebeg = bucket_base[b], eend = bucket_base[b + 1];
    int cnt = eend - ebeg;
    int node0 = b << BSH;
    if (threadIdx.x < 128) hist[threadIdx.x] = 0;
    __syncthreads();
    for (int e = threadIdx.x; e < cnt; e += 512)
        atomicAdd(&hist[(epack[ebeg + e] >> 16) & 127], 1);
    __syncthreads();
    if (threadIdx.x < 64) {                       // wave 0: scan 128 counters
        int lane = threadIdx.x;
        int carry = 0;
        #pragma unroll
        for (int c = 0; c < 2; ++c) {
            int i = c * 64 + lane;
            int v = hist[i];
            int s = v;
            #pragma unroll
            for (int off = 1; off < 64; off <<= 1) {
                int t = __shfl_up(s, off, 64);
                if (lane >= off) s += t;
            }
            excl[i] = carry + s - v;
            carry += __shfl(s, 63, 64);
        }
        if (lane == 0) excl[128] = carry;
    }
    __syncthreads();
    int nh = n - node0; if (nh > 128) nh = 128;
    for (int i = threadIdx.x; i <= nh; i += 512)
        row_start[node0 + i] = ebeg + excl[i];
    if (threadIdx.x < 128) cursor[threadIdx.x] = excl[threadIdx.x];
    __syncthreads();
    for (int e = threadIdx.x; e < cnt; e += 512) {
        uint32_t p = epack[ebeg + e];
        int r = atomicAdd(&cursor[(p >> 16) & 127], 1);
        int sv = (int)(p & 0xFFFFu);
        if (r < LCCAP) sorted[r] = sv;            // LDS scatter (cheap)
        else edge_src[ebeg + r] = sv;             // safety overflow (never at avg 4194)
    }
    __syncthreads();
    int lim = cnt < LCCAP ? cnt : LCCAP;
    for (int i = threadIdx.x; i < lim; i += 512)
        edge_src[ebeg + i] = sorted[i];           // dense coalesced write
}

// ---------------- routing: wave per node, z in registers, LDS-free ----------------
__device__ __forceinline__ void route_group(const v2f z[4], const v2f c[4], v2f acc[4]) {
    v2f p2 = z[0] * c[0];
    p2 = pk_fma(z[1], c[1], p2);
    p2 = pk_fma(z[2], c[2], p2);
    p2 = pk_fma(z[3], c[3], p2);
    float p = p2[0] + p2[1];
    float ex = __expf(p);               // TAU = 1; |p|<=1 -> no max-subtract
    float sm = dpp_add_xor1(ex);
    sm = dpp_add_xor2(sm);
    sm = dpp_add_xor8(sm);
    float wgt = __fdividef(ex, sm);
    v2f w2 = (v2f){wgt, wgt};
    acc[0] = pk_fma(w2, z[0], acc[0]);
    acc[1] = pk_fma(w2, z[1], acc[1]);
    acc[2] = pk_fma(w2, z[2], acc[2]);
    acc[3] = pk_fma(w2, z[3], acc[3]);
}

__global__ __launch_bounds__(256, 4) void route_kernel(
    const float* __restrict__ h, const int* __restrict__ row_start,
    const int* __restrict__ edge_src, float* __restrict__ out, int n)
{
    int lane = threadIdx.x & 63;
    int wid  = threadIdx.x >> 6;
    int v = blockIdx.x * 4 + wid;
    if (v >= n) return;
    int beg = row_start[v];
    int deg = row_start[v + 1] - beg;
    int nl  = deg < LCAP ? deg : LCAP;
    int ngroups = (nl + 7) >> 3;

    int k  = (lane & 3) | ((lane >> 1) & 4);         // capsule: lane bits 0,1,3
    int eo = ((lane >> 2) & 1) | ((lane >> 3) & 6);  // edge-octet: lane bits 2,4,5

    v2f c[4];
    load8p(c, h + (size_t)v * OUT_D + k * 8);

    v2f z[NG][4];
    #pragma unroll
    for (int g = 0; g < NG; ++g) {
        int e = g * 8 + eo;
        if (e < nl) {
            int s = edge_src[beg + e];
            load8p(z[g], h + (size_t)s * OUT_D + k * 8);
        } else {
            #pragma unroll
            for (int d = 0; d < 4; ++d) z[g][d] = (v2f){0.0f, 0.0f};
        }
    }

    #pragma unroll
    for (int it = 0; it < ROUTIT; ++it) {
        v2f acc[4] = {{0,0},{0,0},{0,0},{0,0}};
        #pragma unroll
        for (int g = 0; g < NG; ++g)
            if (g < ngroups) route_group(z[g], c, acc);   // wave-uniform guard
        if (deg > LCAP) {
            for (int e0 = LCAP; e0 < deg; e0 += 8) {
                int e = e0 + eo;
                v2f zt[4] = {{0,0},{0,0},{0,0},{0,0}};
                if (e < deg) {
                    int s = edge_src[beg + e];
                    load8p(zt, h + (size_t)s * OUT_D + k * 8);
                }
                route_group(zt, c, acc);
            }
        }
        float ss = 0.0f;
        #pragma unroll
        for (int d = 0; d < 8; ++d) {
            float a = acc[d >> 1][d & 1];
            a = swz_add_xor4(a);
            a = swz_add_xor16(a);
            a += __shfl_xor(a, 32, 64);
            float cv = c[d >> 1][d & 1] + a;
            c[d >> 1][d & 1] = cv;
            ss = fmaf(cv, cv, ss);
        }
        float inv = 1.0f / fmaxf(sqrtf(ss), 1e-12f);
        v2f inv2 = (v2f){inv, inv};
        #pragma unroll
        for (int j = 0; j < 4; ++j) c[j] *= inv2;
    }
    if (eo == 0) {                                   // lanes {0-3, 8-11} hold k=0..7
        float* op = out + (size_t)v * OUT_D + k * 8;
        float4 o1, o2;
        o1.x=c[0][0]; o1.y=c[0][1]; o1.z=c[1][0]; o1.w=c[1][1];
        o2.x=c[2][0]; o2.y=c[2][1]; o2.z=c[3][0]; o2.w=c[3][1];
        *(float4*)op = o1;
        *(float4*)(op + 4) = o2;
    }
}

// ---------------- launch ----------------
extern "C" void kernel_launch(void* const* d_in, const int* in_sizes, int n_in,
                              void* d_out, int out_size, void* d_ws, size_t ws_size,
                              hipStream_t stream)
{
    const float* x       = (const float*)d_in[0];
    const int*   src_trg = (const int*)d_in[1];
    const float* w       = (const float*)d_in[2];
    const float* bias    = (const float*)d_in[3];
    float*       out     = (float*)d_out;

    int n = in_sizes[0] / IN_DIM;   // 50000
    int m = in_sizes[1] / 2;        // 1638400
    int m4 = m >> 2;
    int nb = (n + 127) >> BSH;      // 391 buckets
    const int* trg = src_trg;       // row 0 = trg
    const int* src = src_trg + m;   // row 1 = src

    char* wsb = (char*)d_ws;
    size_t off = 0;
    float*    h        = (float*)(wsb + off);    off += (size_t)n * OUT_D * sizeof(float);
    int*      rowstart = (int*)(wsb + off);      off += (size_t)(n + 1) * sizeof(int);
    off = (off + 255) & ~(size_t)255;
    int*      edgesrc  = (int*)(wsb + off);      off += (size_t)m * sizeof(int);
    off = (off + 255) & ~(size_t)255;
    uint32_t* epack    = (uint32_t*)(wsb + off); off += (size_t)m * sizeof(uint32_t);
    int*      bcounts  = (int*)(wsb + off);      off += (size_t)(nb + 1) * sizeof(int);
    int*      bbase    = (int*)(wsb + off);      off += (size_t)(nb + 1) * sizeof(int);
    int*      bcursor  = (int*)(wsb + off);      off += (size_t)(nb + 1) * sizeof(int);

    hipMemsetAsync(bcounts, 0, (size_t)(nb + 1) * sizeof(int), stream);
    gemm_norm_kernel<<<(n + 255) / 256, 512, 0, stream>>>(x, w, bias, h, n);
    bucket_hist_kernel<<<256, 256, 0, stream>>>(trg, m4, bcounts, nb);
    bucket_scan_kernel<<<1, 64, 0, stream>>>(bcounts, bbase, bcursor, nb, n, m, rowstart);
    partition_kernel<<<(m + PEDGES - 1) / PEDGES, 1024, 0, stream>>>(trg, src, m4, epack, bcursor, nb);
    local_csr_kernel<<<nb, 512, 0, stream>>>(epack, bbase, rowstart, edgesrc, n);
    route_kernel<<<(n + 3) / 4, 256, 0, stream>>>(h, rowstart, edgesrc, out, n);
}